// Round 12
// baseline (379.430 us; speedup 1.0000x reference)
//
#include <hip/hip_runtime.h>
#include <hip/hip_bf16.h>

#define NEG_SLOPE 0.2f

typedef short bf16x8 __attribute__((ext_vector_type(8)));
typedef float f32x4 __attribute__((ext_vector_type(4)));

__device__ __forceinline__ float b2f(__hip_bfloat16 b) { return __bfloat162float(b); }

__device__ __forceinline__ float loadF(const void* p, int i, bool f32) {
    return f32 ? ((const float*)p)[i] : b2f(((const __hip_bfloat16*)p)[i]);
}

__device__ __forceinline__ void getSD(const int* ei, int e, int E, bool i64, int N,
                                      int& s, int& d) {
    if (e < E) {
        if (i64) { s = ei[2 * e]; d = ei[2 * (E + e)]; }
        else     { s = ei[e];     d = ei[E + e]; }
    } else { s = e - E; d = s; }
    s = min(max(s, 0), N - 1);
    d = min(max(d, 0), N - 1);
}

__device__ __forceinline__ float lrelu(float v) { return v >= 0.f ? v : NEG_SLOPE * v; }
// exp without max-subtraction: logits ~N(0,1.5); clamp for overflow safety.
__device__ __forceinline__ float eexp(float v) { return __expf(fminf(v, 80.f)); }

__device__ __forceinline__ float bfLo(unsigned u) { return __uint_as_float(u << 16); }
__device__ __forceinline__ float bfHi(unsigned u) { return __uint_as_float(u & 0xffff0000u); }

// block 0: flags[0]=1 if float inputs are f32; block 1: flags[1]=1 if edges int64
__global__ void detect_kernel(const void* x, const int* ei, int* flags) {
    if (blockIdx.x == 0) {
        int bad = 0;
        for (int i = threadIdx.x; i < 8192; i += 256) {
            unsigned short u = ((const unsigned short*)x)[i];
            if (((u >> 7) & 0xFF) >= 140) bad = 1;
        }
        if (__ballot(bad) != 0ull && (threadIdx.x & 63) == 0) atomicOr(&flags[0], 1);
    } else {
        __shared__ int cnt;
        if (threadIdx.x == 0) cnt = 0;
        __syncthreads();
        int z = 0;
        for (int i = threadIdx.x; i < 4096; i += 256)
            if (ei[2 * i + 1] == 0) ++z;
        atomicAdd(&cnt, z);
        __syncthreads();
        if (threadIdx.x == 0 && cnt >= 2048) atomicOr(&flags[1], 1);
    }
}

// one kernel: xbf cast | W1t transpose | W2t transpose
__global__ void prep_kernel(const void* __restrict__ x, const void* __restrict__ W1,
                            const void* __restrict__ W2, const int* __restrict__ flags,
                            __hip_bfloat16* __restrict__ xbf,
                            __hip_bfloat16* __restrict__ W1t,
                            __hip_bfloat16* __restrict__ W2t, int nx) {
    const bool f32 = (flags[0] != 0);
    int i = blockIdx.x * 256 + threadIdx.x;
    if (i < nx) {
        xbf[i] = __float2bfloat16(loadF(x, i, f32));
    } else if (i < nx + 256 * 128) {
        int t = i - nx, c = t >> 7, k = t & 127;
        W1t[c * 128 + k] = __float2bfloat16(loadF(W1, k * 256 + c, f32));
    } else if (i < nx + 256 * 128 + 64 * 256) {
        int t = i - nx - 256 * 128, c = t >> 8, k = t & 255;
        W2t[c * 256 + k] = __float2bfloat16(loadF(W2, k * 64 + c, f32));
    }
}

// ---------------- CSR build ----------------

__global__ void count_kernel(const int* __restrict__ ei, int E, int N,
                             const int* __restrict__ flags,
                             int* __restrict__ counts) {
    const bool i64 = (flags[1] != 0);
    int e = blockIdx.x * blockDim.x + threadIdx.x;
    if (e >= E + N) return;
    int s, d;
    getSD(ei, e, E, i64, N, s, d);
    atomicAdd(&counts[d], 1);
}

__global__ void scanA_kernel(const int* __restrict__ counts,
                             int* __restrict__ blocksum, int N) {
    int b = blockIdx.x;
    int i = b * 256 + threadIdx.x;
    int v = (i < N) ? counts[i] : 0;
    for (int off = 32; off >= 1; off >>= 1) v += __shfl_down(v, off, 64);
    __shared__ int ws[4];
    if ((threadIdx.x & 63) == 0) ws[threadIdx.x >> 6] = v;
    __syncthreads();
    if (threadIdx.x == 0) blocksum[b] = ws[0] + ws[1] + ws[2] + ws[3];
}

__global__ void scanB_kernel(const int* __restrict__ blocksum,
                             int* __restrict__ blockoff, int nb) {
    int t = threadIdx.x;  // 1024
    int own = (t < nb) ? blocksum[t] : 0;
    int v = own;
    int lane = t & 63, w = t >> 6;
    for (int d = 1; d < 64; d <<= 1) {
        int u = __shfl_up(v, d, 64);
        if (lane >= d) v += u;
    }
    __shared__ int wsum[16];
    if (lane == 63) wsum[w] = v;
    __syncthreads();
    if (w == 0 && lane < 16) {
        int s = wsum[lane];
        for (int d = 1; d < 16; d <<= 1) {
            int u = __shfl_up(s, d, 64);
            if (lane >= d) s += u;
        }
        wsum[lane] = s;
    }
    __syncthreads();
    int woff = (w > 0) ? wsum[w - 1] : 0;
    if (t < nb) blockoff[t] = woff + v - own;
}

__global__ void scanC_kernel(const int* __restrict__ counts,
                             const int* __restrict__ blockoff,
                             int* __restrict__ row_start,
                             int* __restrict__ cursor, int N, int Et) {
    int b = blockIdx.x;
    int t = threadIdx.x;
    int i = b * 256 + t;
    int own = (i < N) ? counts[i] : 0;
    int v = own;
    int lane = t & 63, w = t >> 6;
    for (int d = 1; d < 64; d <<= 1) {
        int u = __shfl_up(v, d, 64);
        if (lane >= d) v += u;
    }
    __shared__ int ws[4];
    if (lane == 63) ws[w] = v;
    __syncthreads();
    int woff = 0;
#pragma unroll
    for (int q = 0; q < 4; ++q) woff += (q < w) ? ws[q] : 0;
    int exc = blockoff[b] + woff + v - own;
    if (i < N) { row_start[i] = exc; cursor[i] = exc; }
    if (i == N - 1) row_start[N] = Et;
}

__global__ void scatter_kernel(const int* __restrict__ ei, int E, int N,
                               const int* __restrict__ flags,
                               int* __restrict__ cursor,
                               int* __restrict__ csr_src) {
    const bool i64 = (flags[1] != 0);
    int e = blockIdx.x * blockDim.x + threadIdx.x;
    if (e >= E + N) return;
    int s, d;
    getSD(ei, e, E, i64, N, s, d);
    int pos = atomicAdd(&cursor[d], 1);
    csr_src[pos] = s;
}

// ---------------- Layer 1 GEMM via MFMA ----------------
__global__ void gemm1_kernel(const __hip_bfloat16* __restrict__ xbf,
                             const __hip_bfloat16* __restrict__ W1t,
                             const void* __restrict__ att_src,
                             const void* __restrict__ att_dst,
                             const int* __restrict__ flags,
                             __hip_bfloat16* __restrict__ h1,
                             float* __restrict__ a_s,
                             float* __restrict__ a_d, int N) {
    const bool f32 = (flags[0] != 0);
    const int n0 = blockIdx.x * 16;
    const int w = threadIdx.x >> 6;
    const int lane = threadIdx.x & 63;
    const int q = lane >> 4;
    const int cl = lane & 15;

    bf16x8 a[4];
#pragma unroll
    for (int kc = 0; kc < 4; ++kc) {
        int n = min(n0 + cl, N - 1);
        a[kc] = *(const bf16x8*)(xbf + (size_t)n * 128 + kc * 32 + q * 8);
    }
    f32x4 acc[4];
#pragma unroll
    for (int ct = 0; ct < 4; ++ct) acc[ct] = (f32x4){0.f, 0.f, 0.f, 0.f};
#pragma unroll
    for (int kc = 0; kc < 4; ++kc) {
#pragma unroll
        for (int ct = 0; ct < 4; ++ct) {
            int col = w * 64 + ct * 16 + cl;
            bf16x8 b = *(const bf16x8*)(W1t + (size_t)col * 128 + kc * 32 + q * 8);
            acc[ct] = __builtin_amdgcn_mfma_f32_16x16x32_bf16(a[kc], b, acc[ct], 0, 0, 0);
        }
    }
    float asw[4], adw[4];
#pragma unroll
    for (int ct = 0; ct < 4; ++ct) {
        int col = w * 64 + ct * 16 + cl;
        asw[ct] = loadF(att_src, col, f32);
        adw[ct] = loadF(att_dst, col, f32);
    }
#pragma unroll
    for (int r = 0; r < 4; ++r) {
        int n = n0 + q * 4 + r;
        if (n < N) {
#pragma unroll
            for (int ct = 0; ct < 4; ++ct)
                h1[(size_t)n * 256 + w * 64 + ct * 16 + cl] = __float2bfloat16(acc[ct][r]);
        }
        float pas = acc[0][r] * asw[0] + acc[1][r] * asw[1]
                  + acc[2][r] * asw[2] + acc[3][r] * asw[3];
        float pad = acc[0][r] * adw[0] + acc[1][r] * adw[1]
                  + acc[2][r] * adw[2] + acc[3][r] * adw[3];
#pragma unroll
        for (int m = 1; m <= 8; m <<= 1) {
            pas += __shfl_xor(pas, m, 64);
            pad += __shfl_xor(pad, m, 64);
        }
        if (cl == 0 && n < N) {
            a_s[n * 4 + w] = pas;
            a_d[n * 4 + w] = pad;
        }
    }
}

// ---------------- fused layer-1 aggregation: no-max softmax, unroll x8 ----------------
__global__ void fused1_kernel(const int* __restrict__ row_start,
                              const int* __restrict__ csr_src,
                              const float* __restrict__ a_s,
                              const float* __restrict__ a_d,
                              const __hip_bfloat16* __restrict__ h1,
                              const void* __restrict__ bias1,
                              const int* __restrict__ flags,
                              __hip_bfloat16* __restrict__ h1act, int N) {
    const bool f32 = (flags[0] != 0);
    int n = blockIdx.x * 4 + (threadIdx.x >> 6);
    if (n >= N) return;
    int lane = threadIdx.x & 63;
    int h = lane >> 4;
    int lo = row_start[n], hi = row_start[n + 1];
    float ad = a_d[n * 4 + h];
    float l = 0.f, a0 = 0.f, a1 = 0.f, a2 = 0.f, a3 = 0.f;
    int t = lo;
    for (; t + 7 < hi; t += 8) {
        int s[8];
        uint2 r[8];
        float w[8];
#pragma unroll
        for (int i = 0; i < 8; ++i) s[i] = csr_src[t + i];
#pragma unroll
        for (int i = 0; i < 8; ++i)
            r[i] = *(const uint2*)(h1 + (size_t)s[i] * 256 + lane * 4);
#pragma unroll
        for (int i = 0; i < 8; ++i)
            w[i] = eexp(lrelu(a_s[s[i] * 4 + h] + ad));
#pragma unroll
        for (int i = 0; i < 8; ++i) {
            l  += w[i];
            a0 += w[i] * bfLo(r[i].x);
            a1 += w[i] * bfHi(r[i].x);
            a2 += w[i] * bfLo(r[i].y);
            a3 += w[i] * bfHi(r[i].y);
        }
    }
    for (; t < hi; ++t) {
        int s1 = csr_src[t];
        uint2 r1 = *(const uint2*)(h1 + (size_t)s1 * 256 + lane * 4);
        float w1 = eexp(lrelu(a_s[s1 * 4 + h] + ad));
        l += w1;
        a0 += w1 * bfLo(r1.x);
        a1 += w1 * bfHi(r1.x);
        a2 += w1 * bfLo(r1.y);
        a3 += w1 * bfHi(r1.y);
    }
    float inv = 1.f / (l + 1e-16f);
    float o[4] = {a0 * inv, a1 * inv, a2 * inv, a3 * inv};
#pragma unroll
    for (int i = 0; i < 4; ++i) {
        float val = o[i] + loadF(bias1, lane * 4 + i, f32);
        val = val > 0.f ? val : (__expf(val) - 1.f);
        h1act[(size_t)n * 256 + lane * 4 + i] = __float2bfloat16(val);
    }
}

// ---------------- Layer 2 GEMM via MFMA (bf16 h2 output) ----------------
__global__ void gemm2_kernel(const __hip_bfloat16* __restrict__ h1act,
                             const __hip_bfloat16* __restrict__ W2t,
                             const void* __restrict__ att_src2,
                             const void* __restrict__ att_dst2,
                             const int* __restrict__ flags,
                             __hip_bfloat16* __restrict__ h2b,
                             float* __restrict__ a_s2,
                             float* __restrict__ a_d2, int N) {
    const bool f32 = (flags[0] != 0);
    const int w = threadIdx.x >> 6;
    const int n0 = blockIdx.x * 64 + w * 16;
    const int lane = threadIdx.x & 63;
    const int q = lane >> 4;
    const int cl = lane & 15;

    f32x4 acc[4];
#pragma unroll
    for (int ct = 0; ct < 4; ++ct) acc[ct] = (f32x4){0.f, 0.f, 0.f, 0.f};
    const int an = min(n0 + cl, N - 1);
#pragma unroll
    for (int kc = 0; kc < 8; ++kc) {
        bf16x8 a = *(const bf16x8*)(h1act + (size_t)an * 256 + kc * 32 + q * 8);
#pragma unroll
        for (int ct = 0; ct < 4; ++ct) {
            int col = ct * 16 + cl;
            bf16x8 b = *(const bf16x8*)(W2t + (size_t)col * 256 + kc * 32 + q * 8);
            acc[ct] = __builtin_amdgcn_mfma_f32_16x16x32_bf16(a, b, acc[ct], 0, 0, 0);
        }
    }
    float asw[4], adw[4];
#pragma unroll
    for (int ct = 0; ct < 4; ++ct) {
        asw[ct] = loadF(att_src2, ct * 16 + cl, f32);
        adw[ct] = loadF(att_dst2, ct * 16 + cl, f32);
    }
#pragma unroll
    for (int r = 0; r < 4; ++r) {
        int n = min(n0 + q * 4 + r, N - 1);
#pragma unroll
        for (int ct = 0; ct < 4; ++ct)
            h2b[(size_t)n * 64 + ct * 16 + cl] = __float2bfloat16(acc[ct][r]);
        float pas = acc[0][r] * asw[0] + acc[1][r] * asw[1]
                  + acc[2][r] * asw[2] + acc[3][r] * asw[3];
        float pad = acc[0][r] * adw[0] + acc[1][r] * adw[1]
                  + acc[2][r] * adw[2] + acc[3][r] * adw[3];
#pragma unroll
        for (int m = 1; m <= 8; m <<= 1) {
            pas += __shfl_xor(pas, m, 64);
            pad += __shfl_xor(pad, m, 64);
        }
        if (cl == 0) { a_s2[n] = pas; a_d2[n] = pad; }
    }
}

// ---------------- fused layer-2: bf16 gather, half-wave per edge ----------------
// 4 waves/block = 4 dst nodes. Within a wave: lanes 0-31 process even edges,
// lanes 32-63 odd edges (one 4B uint = 2 bf16 cols per lane); shfl_xor(32) merge.
__global__ void fused2_kernel(const int* __restrict__ row_start,
                              const int* __restrict__ csr_src,
                              const float* __restrict__ a_s,
                              const float* __restrict__ a_d,
                              const __hip_bfloat16* __restrict__ h2b,
                              const void* __restrict__ bias2,
                              const int* __restrict__ flags,
                              float* __restrict__ out, int N) {
    const bool f32 = (flags[0] != 0);
    int n = blockIdx.x * 4 + (threadIdx.x >> 6);
    if (n >= N) return;
    int lane = threadIdx.x & 63;
    int half = lane >> 5;   // 0: even edges, 1: odd edges
    int hl = lane & 31;     // owns cols 2*hl, 2*hl+1
    int lo = row_start[n], hi = row_start[n + 1];
    float ad = a_d[n];
    float l = 0.f, acc0 = 0.f, acc1 = 0.f;
    int t = lo + half;
    for (; t + 2 < hi; t += 4) {
        int s1 = csr_src[t], s2 = csr_src[t + 2];
        unsigned u1 = *(const unsigned*)(h2b + (size_t)s1 * 64 + hl * 2);
        unsigned u2 = *(const unsigned*)(h2b + (size_t)s2 * 64 + hl * 2);
        float w1 = eexp(lrelu(a_s[s1] + ad));
        float w2 = eexp(lrelu(a_s[s2] + ad));
        l += w1 + w2;
        acc0 += w1 * bfLo(u1) + w2 * bfLo(u2);
        acc1 += w1 * bfHi(u1) + w2 * bfHi(u2);
    }
    for (; t < hi; t += 2) {
        int s1 = csr_src[t];
        unsigned u1 = *(const unsigned*)(h2b + (size_t)s1 * 64 + hl * 2);
        float w1 = eexp(lrelu(a_s[s1] + ad));
        l += w1;
        acc0 += w1 * bfLo(u1);
        acc1 += w1 * bfHi(u1);
    }
    l    += __shfl_xor(l, 32, 64);
    acc0 += __shfl_xor(acc0, 32, 64);
    acc1 += __shfl_xor(acc1, 32, 64);
    if (half == 0) {
        float inv = 1.f / (l + 1e-16f);
        out[(size_t)n * 64 + hl * 2]     = acc0 * inv + loadF(bias2, hl * 2, f32);
        out[(size_t)n * 64 + hl * 2 + 1] = acc1 * inv + loadF(bias2, hl * 2 + 1, f32);
    }
}

__global__ void sentinel_kernel(float* __restrict__ out, int n, float C) {
    int i = blockIdx.x * blockDim.x + threadIdx.x;
    if (i < n) out[i] = C;
}

static inline size_t al256(size_t x) { return (x + 255) & ~(size_t)255; }

extern "C" void kernel_launch(void* const* d_in, const int* in_sizes, int n_in,
                              void* d_out, int out_size, void* d_ws, size_t ws_size,
                              hipStream_t stream) {
    const void* x     = d_in[0];
    const int*  ei    = (const int*)d_in[1];
    const void* W1    = d_in[2];
    const void* as1w  = d_in[3];
    const void* ad1w  = d_in[4];
    const void* bias1 = d_in[5];
    const void* W2    = d_in[6];
    const void* as2w  = d_in[7];
    const void* ad2w  = d_in[8];
    const void* bias2 = d_in[9];

    const int N  = in_sizes[0] / 128;  // 50000
    const int E  = in_sizes[1] / 2;    // 800000
    const int Et = E + N;
    const int NCH = (N + 255) / 256;

    char* p = (char*)d_ws;
    int* flags = (int*)p;                       p += 256;
    int* counts = (int*)p;                      p += al256((size_t)N * 4);
    int* row_start = (int*)p;                   p += al256(((size_t)N + 1) * 4);
    int* cursor = (int*)p;                      p += al256((size_t)N * 4);
    int* blocksum = (int*)p;                    p += al256((size_t)NCH * 4);
    int* blockoff = (int*)p;                    p += al256((size_t)NCH * 4);
    int* csr_src = (int*)p;                     p += al256((size_t)Et * 4);
    float* a_s1 = (float*)p;                    p += al256((size_t)N * 4 * 4);
    float* a_d1 = (float*)p;                    p += al256((size_t)N * 4 * 4);
    __hip_bfloat16* xbf = (__hip_bfloat16*)p;   p += al256((size_t)N * 128 * 2);
    __hip_bfloat16* W1t = (__hip_bfloat16*)p;   p += al256(256 * 128 * 2);
    __hip_bfloat16* W2t = (__hip_bfloat16*)p;   p += al256(64 * 256 * 2);
    char* h1_region = p;
    __hip_bfloat16* h1 = (__hip_bfloat16*)p;    p += al256((size_t)N * 256 * 2);
    __hip_bfloat16* h1act = (__hip_bfloat16*)p; p += al256((size_t)N * 256 * 2);
    float* a_s2 = (float*)p;                    p += al256((size_t)N * 4);
    float* a_d2 = (float*)p;                    p += al256((size_t)N * 4);
    __hip_bfloat16* h2b = (__hip_bfloat16*)h1_region;  // overlay: h1 dead after fused1

    const size_t need = (size_t)(p - (char*)d_ws);
    if (ws_size < need) {
        sentinel_kernel<<<(out_size + 255) / 256, 256, 0, stream>>>(
            (float*)d_out, out_size, 5.0f);
        return;
    }

    hipMemsetAsync(flags, 0, 8, stream);
    detect_kernel<<<2, 256, 0, stream>>>(x, ei, flags);

    const int nx = N * 128;
    prep_kernel<<<(nx + 256 * 128 + 64 * 256 + 255) / 256, 256, 0, stream>>>(
        x, W1, W2, flags, xbf, W1t, W2t, nx);

    hipMemsetAsync(counts, 0, (size_t)N * 4, stream);
    const int TB = 256, GB = (Et + TB - 1) / TB;
    count_kernel<<<GB, TB, 0, stream>>>(ei, E, N, flags, counts);
    scanA_kernel<<<NCH, 256, 0, stream>>>(counts, blocksum, N);
    scanB_kernel<<<1, 1024, 0, stream>>>(blocksum, blockoff, NCH);
    scanC_kernel<<<NCH, 256, 0, stream>>>(counts, blockoff, row_start, cursor, N, Et);
    scatter_kernel<<<GB, TB, 0, stream>>>(ei, E, N, flags, cursor, csr_src);

    gemm1_kernel<<<(N + 15) / 16, 256, 0, stream>>>(xbf, W1t, as1w, ad1w, flags,
                                                    h1, a_s1, a_d1, N);
    fused1_kernel<<<(N + 3) / 4, 256, 0, stream>>>(row_start, csr_src, a_s1, a_d1,
                                                   h1, bias1, flags, h1act, N);
    gemm2_kernel<<<(N + 63) / 64, 256, 0, stream>>>(h1act, W2t, as2w, ad2w, flags,
                                                    h2b, a_s2, a_d2, N);
    fused2_kernel<<<(N + 3) / 4, 256, 0, stream>>>(row_start, csr_src, a_s2, a_d2,
                                                   h2b, bias2, flags, (float*)d_out, N);
}

// Round 13
// 358.852 us; speedup vs baseline: 1.0573x; 1.0573x over previous
//
#include <hip/hip_runtime.h>
#include <hip/hip_bf16.h>

#define NEG_SLOPE 0.2f

typedef short bf16x8 __attribute__((ext_vector_type(8)));
typedef float f32x4 __attribute__((ext_vector_type(4)));

union BF8 { bf16x8 v; __hip_bfloat16 e[8]; };

__device__ __forceinline__ float b2f(__hip_bfloat16 b) { return __bfloat162float(b); }

__device__ __forceinline__ float loadF(const void* p, int i, bool f32) {
    return f32 ? ((const float*)p)[i] : b2f(((const __hip_bfloat16*)p)[i]);
}

__device__ __forceinline__ void getSD(const int* ei, int e, int E, bool i64, int N,
                                      int& s, int& d) {
    if (e < E) {
        if (i64) { s = ei[2 * e]; d = ei[2 * (E + e)]; }
        else     { s = ei[e];     d = ei[E + e]; }
    } else { s = e - E; d = s; }
    s = min(max(s, 0), N - 1);
    d = min(max(d, 0), N - 1);
}

__device__ __forceinline__ float lrelu(float v) { return v >= 0.f ? v : NEG_SLOPE * v; }
// exp without max-subtraction: logits ~N(0,1.5); clamp for overflow safety.
__device__ __forceinline__ float eexp(float v) { return __expf(fminf(v, 80.f)); }

__device__ __forceinline__ float bfLo(unsigned u) { return __uint_as_float(u << 16); }
__device__ __forceinline__ float bfHi(unsigned u) { return __uint_as_float(u & 0xffff0000u); }

// block 0 -> flags[0] (floats f32?); block 1 -> flags[1] (edges int64?);
// blocks 2.. zero the counts array. Deterministic writes, no pre-memset needed.
__global__ void detect_kernel(const void* x, const int* ei, int* flags,
                              int* counts, int N) {
    if (blockIdx.x == 0) {
        int bad = 0;
        for (int i = threadIdx.x; i < 8192; i += 256) {
            unsigned short u = ((const unsigned short*)x)[i];
            if (((u >> 7) & 0xFF) >= 140) bad = 1;
        }
        __shared__ int r[4];
        unsigned long long m = __ballot(bad);
        if ((threadIdx.x & 63) == 0) r[threadIdx.x >> 6] = (m != 0ull);
        __syncthreads();
        if (threadIdx.x == 0) flags[0] = (r[0] | r[1] | r[2] | r[3]) ? 1 : 0;
    } else if (blockIdx.x == 1) {
        __shared__ int cnt;
        if (threadIdx.x == 0) cnt = 0;
        __syncthreads();
        int z = 0;
        for (int i = threadIdx.x; i < 4096; i += 256)
            if (ei[2 * i + 1] == 0) ++z;
        atomicAdd(&cnt, z);
        __syncthreads();
        if (threadIdx.x == 0) flags[1] = (cnt >= 2048) ? 1 : 0;
    } else {
        int i = (blockIdx.x - 2) * 256 + threadIdx.x;
        if (i < N) counts[i] = 0;
    }
}

// weight transposes only (x is consumed directly by gemm1)
__global__ void prep_kernel(const void* __restrict__ W1, const void* __restrict__ W2,
                            const int* __restrict__ flags,
                            __hip_bfloat16* __restrict__ W1t,
                            __hip_bfloat16* __restrict__ W2t) {
    const bool f32 = (flags[0] != 0);
    int i = blockIdx.x * 256 + threadIdx.x;
    if (i < 256 * 128) {
        int c = i >> 7, k = i & 127;
        W1t[c * 128 + k] = __float2bfloat16(loadF(W1, k * 256 + c, f32));
    } else if (i < 256 * 128 + 64 * 256) {
        int t = i - 256 * 128, c = t >> 8, k = t & 255;
        W2t[c * 256 + k] = __float2bfloat16(loadF(W2, k * 64 + c, f32));
    }
}

// ---------------- CSR build ----------------

__global__ void count_kernel(const int* __restrict__ ei, int E, int N,
                             const int* __restrict__ flags,
                             int* __restrict__ counts) {
    const bool i64 = (flags[1] != 0);
    int e = blockIdx.x * blockDim.x + threadIdx.x;
    if (e >= E + N) return;
    int s, d;
    getSD(ei, e, E, i64, N, s, d);
    atomicAdd(&counts[d], 1);
}

__global__ void scanA_kernel(const int* __restrict__ counts,
                             int* __restrict__ blocksum, int N) {
    int b = blockIdx.x;
    int i = b * 256 + threadIdx.x;
    int v = (i < N) ? counts[i] : 0;
    for (int off = 32; off >= 1; off >>= 1) v += __shfl_down(v, off, 64);
    __shared__ int ws[4];
    if ((threadIdx.x & 63) == 0) ws[threadIdx.x >> 6] = v;
    __syncthreads();
    if (threadIdx.x == 0) blocksum[b] = ws[0] + ws[1] + ws[2] + ws[3];
}

__global__ void scanB_kernel(const int* __restrict__ blocksum,
                             int* __restrict__ blockoff, int nb) {
    int t = threadIdx.x;  // 1024
    int own = (t < nb) ? blocksum[t] : 0;
    int v = own;
    int lane = t & 63, w = t >> 6;
    for (int d = 1; d < 64; d <<= 1) {
        int u = __shfl_up(v, d, 64);
        if (lane >= d) v += u;
    }
    __shared__ int wsum[16];
    if (lane == 63) wsum[w] = v;
    __syncthreads();
    if (w == 0 && lane < 16) {
        int s = wsum[lane];
        for (int d = 1; d < 16; d <<= 1) {
            int u = __shfl_up(s, d, 64);
            if (lane >= d) s += u;
        }
        wsum[lane] = s;
    }
    __syncthreads();
    int woff = (w > 0) ? wsum[w - 1] : 0;
    if (t < nb) blockoff[t] = woff + v - own;
}

__global__ void scanC_kernel(const int* __restrict__ counts,
                             const int* __restrict__ blockoff,
                             int* __restrict__ row_start,
                             int* __restrict__ cursor, int N, int Et) {
    int b = blockIdx.x;
    int t = threadIdx.x;
    int i = b * 256 + t;
    int own = (i < N) ? counts[i] : 0;
    int v = own;
    int lane = t & 63, w = t >> 6;
    for (int d = 1; d < 64; d <<= 1) {
        int u = __shfl_up(v, d, 64);
        if (lane >= d) v += u;
    }
    __shared__ int ws[4];
    if (lane == 63) ws[w] = v;
    __syncthreads();
    int woff = 0;
#pragma unroll
    for (int q = 0; q < 4; ++q) woff += (q < w) ? ws[q] : 0;
    int exc = blockoff[b] + woff + v - own;
    if (i < N) { row_start[i] = exc; cursor[i] = exc; }
    if (i == N - 1) row_start[N] = Et;
}

__global__ void scatter_kernel(const int* __restrict__ ei, int E, int N,
                               const int* __restrict__ flags,
                               int* __restrict__ cursor,
                               int* __restrict__ csr_src) {
    const bool i64 = (flags[1] != 0);
    int e = blockIdx.x * blockDim.x + threadIdx.x;
    if (e >= E + N) return;
    int s, d;
    getSD(ei, e, E, i64, N, s, d);
    int pos = atomicAdd(&cursor[d], 1);
    csr_src[pos] = s;
}

// ---------------- Layer 1 GEMM via MFMA (reads x directly) ----------------
__global__ void gemm1_kernel(const void* __restrict__ x,
                             const __hip_bfloat16* __restrict__ W1t,
                             const void* __restrict__ att_src,
                             const void* __restrict__ att_dst,
                             const int* __restrict__ flags,
                             __hip_bfloat16* __restrict__ h1,
                             float* __restrict__ a_s,
                             float* __restrict__ a_d, int N) {
    const bool f32 = (flags[0] != 0);
    const int n0 = blockIdx.x * 16;
    const int w = threadIdx.x >> 6;
    const int lane = threadIdx.x & 63;
    const int q = lane >> 4;
    const int cl = lane & 15;

    bf16x8 a[4];
    const int an = min(n0 + cl, N - 1);
    if (f32) {
        const float* xp = (const float*)x + (size_t)an * 128;
#pragma unroll
        for (int kc = 0; kc < 4; ++kc) {
            f32x4 v0 = *(const f32x4*)(xp + kc * 32 + q * 8);
            f32x4 v1 = *(const f32x4*)(xp + kc * 32 + q * 8 + 4);
            BF8 t;
#pragma unroll
            for (int i = 0; i < 4; ++i) {
                t.e[i]     = __float2bfloat16(v0[i]);
                t.e[i + 4] = __float2bfloat16(v1[i]);
            }
            a[kc] = t.v;
        }
    } else {
        const __hip_bfloat16* xp = (const __hip_bfloat16*)x + (size_t)an * 128;
#pragma unroll
        for (int kc = 0; kc < 4; ++kc)
            a[kc] = *(const bf16x8*)(xp + kc * 32 + q * 8);
    }
    f32x4 acc[4];
#pragma unroll
    for (int ct = 0; ct < 4; ++ct) acc[ct] = (f32x4){0.f, 0.f, 0.f, 0.f};
#pragma unroll
    for (int kc = 0; kc < 4; ++kc) {
#pragma unroll
        for (int ct = 0; ct < 4; ++ct) {
            int col = w * 64 + ct * 16 + cl;
            bf16x8 b = *(const bf16x8*)(W1t + (size_t)col * 128 + kc * 32 + q * 8);
            acc[ct] = __builtin_amdgcn_mfma_f32_16x16x32_bf16(a[kc], b, acc[ct], 0, 0, 0);
        }
    }
    float asw[4], adw[4];
#pragma unroll
    for (int ct = 0; ct < 4; ++ct) {
        int col = w * 64 + ct * 16 + cl;
        asw[ct] = loadF(att_src, col, f32);
        adw[ct] = loadF(att_dst, col, f32);
    }
#pragma unroll
    for (int r = 0; r < 4; ++r) {
        int n = n0 + q * 4 + r;
        if (n < N) {
#pragma unroll
            for (int ct = 0; ct < 4; ++ct)
                h1[(size_t)n * 256 + w * 64 + ct * 16 + cl] = __float2bfloat16(acc[ct][r]);
        }
        float pas = acc[0][r] * asw[0] + acc[1][r] * asw[1]
                  + acc[2][r] * asw[2] + acc[3][r] * asw[3];
        float pad = acc[0][r] * adw[0] + acc[1][r] * adw[1]
                  + acc[2][r] * adw[2] + acc[3][r] * adw[3];
#pragma unroll
        for (int m = 1; m <= 8; m <<= 1) {
            pas += __shfl_xor(pas, m, 64);
            pad += __shfl_xor(pad, m, 64);
        }
        if (cl == 0 && n < N) {
            a_s[n * 4 + w] = pas;
            a_d[n * 4 + w] = pad;
        }
    }
}

// ---------------- fused layer-1 aggregation: no-max softmax, unroll x4 ----------------
// (x8 unroll regressed: VGPR 40 -> occupancy 52%; x4 keeps VGPR 24 / occ 70%)
__global__ void fused1_kernel(const int* __restrict__ row_start,
                              const int* __restrict__ csr_src,
                              const float* __restrict__ a_s,
                              const float* __restrict__ a_d,
                              const __hip_bfloat16* __restrict__ h1,
                              const void* __restrict__ bias1,
                              const int* __restrict__ flags,
                              __hip_bfloat16* __restrict__ h1act, int N) {
    const bool f32 = (flags[0] != 0);
    int n = blockIdx.x * 4 + (threadIdx.x >> 6);
    if (n >= N) return;
    int lane = threadIdx.x & 63;
    int h = lane >> 4;
    int lo = row_start[n], hi = row_start[n + 1];
    float ad = a_d[n * 4 + h];
    float l = 0.f, a0 = 0.f, a1 = 0.f, a2 = 0.f, a3 = 0.f;
    int t = lo;
    for (; t + 3 < hi; t += 4) {
        int s1 = csr_src[t], s2 = csr_src[t + 1], s3 = csr_src[t + 2], s4 = csr_src[t + 3];
        uint2 r1 = *(const uint2*)(h1 + (size_t)s1 * 256 + lane * 4);
        uint2 r2 = *(const uint2*)(h1 + (size_t)s2 * 256 + lane * 4);
        uint2 r3 = *(const uint2*)(h1 + (size_t)s3 * 256 + lane * 4);
        uint2 r4 = *(const uint2*)(h1 + (size_t)s4 * 256 + lane * 4);
        float w1 = eexp(lrelu(a_s[s1 * 4 + h] + ad));
        float w2 = eexp(lrelu(a_s[s2 * 4 + h] + ad));
        float w3 = eexp(lrelu(a_s[s3 * 4 + h] + ad));
        float w4 = eexp(lrelu(a_s[s4 * 4 + h] + ad));
        l += (w1 + w2) + (w3 + w4);
        a0 += w1 * bfLo(r1.x) + w2 * bfLo(r2.x) + w3 * bfLo(r3.x) + w4 * bfLo(r4.x);
        a1 += w1 * bfHi(r1.x) + w2 * bfHi(r2.x) + w3 * bfHi(r3.x) + w4 * bfHi(r4.x);
        a2 += w1 * bfLo(r1.y) + w2 * bfLo(r2.y) + w3 * bfLo(r3.y) + w4 * bfLo(r4.y);
        a3 += w1 * bfHi(r1.y) + w2 * bfHi(r2.y) + w3 * bfHi(r3.y) + w4 * bfHi(r4.y);
    }
    for (; t < hi; ++t) {
        int s1 = csr_src[t];
        uint2 r1 = *(const uint2*)(h1 + (size_t)s1 * 256 + lane * 4);
        float w1 = eexp(lrelu(a_s[s1 * 4 + h] + ad));
        l += w1;
        a0 += w1 * bfLo(r1.x);
        a1 += w1 * bfHi(r1.x);
        a2 += w1 * bfLo(r1.y);
        a3 += w1 * bfHi(r1.y);
    }
    float inv = 1.f / (l + 1e-16f);
    float o[4] = {a0 * inv, a1 * inv, a2 * inv, a3 * inv};
#pragma unroll
    for (int i = 0; i < 4; ++i) {
        float val = o[i] + loadF(bias1, lane * 4 + i, f32);
        val = val > 0.f ? val : (__expf(val) - 1.f);
        h1act[(size_t)n * 256 + lane * 4 + i] = __float2bfloat16(val);
    }
}

// ---------------- Layer 2 GEMM via MFMA (bf16 h2 output) ----------------
__global__ void gemm2_kernel(const __hip_bfloat16* __restrict__ h1act,
                             const __hip_bfloat16* __restrict__ W2t,
                             const void* __restrict__ att_src2,
                             const void* __restrict__ att_dst2,
                             const int* __restrict__ flags,
                             __hip_bfloat16* __restrict__ h2b,
                             float* __restrict__ a_s2,
                             float* __restrict__ a_d2, int N) {
    const bool f32 = (flags[0] != 0);
    const int w = threadIdx.x >> 6;
    const int n0 = blockIdx.x * 64 + w * 16;
    const int lane = threadIdx.x & 63;
    const int q = lane >> 4;
    const int cl = lane & 15;

    f32x4 acc[4];
#pragma unroll
    for (int ct = 0; ct < 4; ++ct) acc[ct] = (f32x4){0.f, 0.f, 0.f, 0.f};
    const int an = min(n0 + cl, N - 1);
#pragma unroll
    for (int kc = 0; kc < 8; ++kc) {
        bf16x8 a = *(const bf16x8*)(h1act + (size_t)an * 256 + kc * 32 + q * 8);
#pragma unroll
        for (int ct = 0; ct < 4; ++ct) {
            int col = ct * 16 + cl;
            bf16x8 b = *(const bf16x8*)(W2t + (size_t)col * 256 + kc * 32 + q * 8);
            acc[ct] = __builtin_amdgcn_mfma_f32_16x16x32_bf16(a, b, acc[ct], 0, 0, 0);
        }
    }
    float asw[4], adw[4];
#pragma unroll
    for (int ct = 0; ct < 4; ++ct) {
        asw[ct] = loadF(att_src2, ct * 16 + cl, f32);
        adw[ct] = loadF(att_dst2, ct * 16 + cl, f32);
    }
#pragma unroll
    for (int r = 0; r < 4; ++r) {
        int n = min(n0 + q * 4 + r, N - 1);
#pragma unroll
        for (int ct = 0; ct < 4; ++ct)
            h2b[(size_t)n * 64 + ct * 16 + cl] = __float2bfloat16(acc[ct][r]);
        float pas = acc[0][r] * asw[0] + acc[1][r] * asw[1]
                  + acc[2][r] * asw[2] + acc[3][r] * asw[3];
        float pad = acc[0][r] * adw[0] + acc[1][r] * adw[1]
                  + acc[2][r] * adw[2] + acc[3][r] * adw[3];
#pragma unroll
        for (int m = 1; m <= 8; m <<= 1) {
            pas += __shfl_xor(pas, m, 64);
            pad += __shfl_xor(pad, m, 64);
        }
        if (cl == 0) { a_s2[n] = pas; a_d2[n] = pad; }
    }
}

// ---------------- fused layer-2: bf16 gather, half-wave per edge ----------------
__global__ void fused2_kernel(const int* __restrict__ row_start,
                              const int* __restrict__ csr_src,
                              const float* __restrict__ a_s,
                              const float* __restrict__ a_d,
                              const __hip_bfloat16* __restrict__ h2b,
                              const void* __restrict__ bias2,
                              const int* __restrict__ flags,
                              float* __restrict__ out, int N) {
    const bool f32 = (flags[0] != 0);
    int n = blockIdx.x * 4 + (threadIdx.x >> 6);
    if (n >= N) return;
    int lane = threadIdx.x & 63;
    int half = lane >> 5;
    int hl = lane & 31;
    int lo = row_start[n], hi = row_start[n + 1];
    float ad = a_d[n];
    float l = 0.f, acc0 = 0.f, acc1 = 0.f;
    int t = lo + half;
    for (; t + 2 < hi; t += 4) {
        int s1 = csr_src[t], s2 = csr_src[t + 2];
        unsigned u1 = *(const unsigned*)(h2b + (size_t)s1 * 64 + hl * 2);
        unsigned u2 = *(const unsigned*)(h2b + (size_t)s2 * 64 + hl * 2);
        float w1 = eexp(lrelu(a_s[s1] + ad));
        float w2 = eexp(lrelu(a_s[s2] + ad));
        l += w1 + w2;
        acc0 += w1 * bfLo(u1) + w2 * bfLo(u2);
        acc1 += w1 * bfHi(u1) + w2 * bfHi(u2);
    }
    for (; t < hi; t += 2) {
        int s1 = csr_src[t];
        unsigned u1 = *(const unsigned*)(h2b + (size_t)s1 * 64 + hl * 2);
        float w1 = eexp(lrelu(a_s[s1] + ad));
        l += w1;
        acc0 += w1 * bfLo(u1);
        acc1 += w1 * bfHi(u1);
    }
    l    += __shfl_xor(l, 32, 64);
    acc0 += __shfl_xor(acc0, 32, 64);
    acc1 += __shfl_xor(acc1, 32, 64);
    if (half == 0) {
        float inv = 1.f / (l + 1e-16f);
        out[(size_t)n * 64 + hl * 2]     = acc0 * inv + loadF(bias2, hl * 2, f32);
        out[(size_t)n * 64 + hl * 2 + 1] = acc1 * inv + loadF(bias2, hl * 2 + 1, f32);
    }
}

__global__ void sentinel_kernel(float* __restrict__ out, int n, float C) {
    int i = blockIdx.x * blockDim.x + threadIdx.x;
    if (i < n) out[i] = C;
}

static inline size_t al256(size_t x) { return (x + 255) & ~(size_t)255; }

extern "C" void kernel_launch(void* const* d_in, const int* in_sizes, int n_in,
                              void* d_out, int out_size, void* d_ws, size_t ws_size,
                              hipStream_t stream) {
    const void* x     = d_in[0];
    const int*  ei    = (const int*)d_in[1];
    const void* W1    = d_in[2];
    const void* as1w  = d_in[3];
    const void* ad1w  = d_in[4];
    const void* bias1 = d_in[5];
    const void* W2    = d_in[6];
    const void* as2w  = d_in[7];
    const void* ad2w  = d_in[8];
    const void* bias2 = d_in[9];

    const int N  = in_sizes[0] / 128;  // 50000
    const int E  = in_sizes[1] / 2;    // 800000
    const int Et = E + N;
    const int NCH = (N + 255) / 256;

    char* p = (char*)d_ws;
    int* flags = (int*)p;                       p += 256;
    int* counts = (int*)p;                      p += al256((size_t)N * 4);
    int* row_start = (int*)p;                   p += al256(((size_t)N + 1) * 4);
    int* cursor = (int*)p;                      p += al256((size_t)N * 4);
    int* blocksum = (int*)p;                    p += al256((size_t)NCH * 4);
    int* blockoff = (int*)p;                    p += al256((size_t)NCH * 4);
    int* csr_src = (int*)p;                     p += al256((size_t)Et * 4);
    float* a_s1 = (float*)p;                    p += al256((size_t)N * 4 * 4);
    float* a_d1 = (float*)p;                    p += al256((size_t)N * 4 * 4);
    __hip_bfloat16* W1t = (__hip_bfloat16*)p;   p += al256(256 * 128 * 2);
    __hip_bfloat16* W2t = (__hip_bfloat16*)p;   p += al256(64 * 256 * 2);
    char* h1_region = p;
    __hip_bfloat16* h1 = (__hip_bfloat16*)p;    p += al256((size_t)N * 256 * 2);
    __hip_bfloat16* h1act = (__hip_bfloat16*)p; p += al256((size_t)N * 256 * 2);
    float* a_s2 = (float*)p;                    p += al256((size_t)N * 4);
    float* a_d2 = (float*)p;                    p += al256((size_t)N * 4);
    __hip_bfloat16* h2b = (__hip_bfloat16*)h1_region;  // overlay: h1 dead after fused1

    const size_t need = (size_t)(p - (char*)d_ws);
    if (ws_size < need) {
        sentinel_kernel<<<(out_size + 255) / 256, 256, 0, stream>>>(
            (float*)d_out, out_size, 5.0f);
        return;
    }

    // detect flags + zero counts in one dispatch (no memsets)
    detect_kernel<<<2 + NCH, 256, 0, stream>>>(x, ei, flags, counts, N);
    prep_kernel<<<(256 * 128 + 64 * 256 + 255) / 256, 256, 0, stream>>>(
        W1, W2, flags, W1t, W2t);

    const int TB = 256, GB = (Et + TB - 1) / TB;
    count_kernel<<<GB, TB, 0, stream>>>(ei, E, N, flags, counts);
    scanA_kernel<<<NCH, 256, 0, stream>>>(counts, blocksum, N);
    scanB_kernel<<<1, 1024, 0, stream>>>(blocksum, blockoff, NCH);
    scanC_kernel<<<NCH, 256, 0, stream>>>(counts, blockoff, row_start, cursor, N, Et);
    scatter_kernel<<<GB, TB, 0, stream>>>(ei, E, N, flags, cursor, csr_src);

    gemm1_kernel<<<(N + 15) / 16, 256, 0, stream>>>(x, W1t, as1w, ad1w, flags,
                                                    h1, a_s1, a_d1, N);
    fused1_kernel<<<(N + 3) / 4, 256, 0, stream>>>(row_start, csr_src, a_s1, a_d1,
                                                   h1, bias1, flags, h1act, N);
    gemm2_kernel<<<(N + 63) / 64, 256, 0, stream>>>(h1act, W2t, as2w, ad2w, flags,
                                                    h2b, a_s2, a_d2, N);
    fused2_kernel<<<(N + 3) / 4, 256, 0, stream>>>(row_start, csr_src, a_s2, a_d2,
                                                   h2b, bias2, flags, (float*)d_out, N);
}